// Round 3
// baseline (147.394 us; speedup 1.0000x reference)
//
#include <hip/hip_runtime.h>
#include <hip/hip_bf16.h>

typedef __hip_bfloat16 bf16;
typedef short bf16x8 __attribute__((ext_vector_type(8)));
typedef float f32x4 __attribute__((ext_vector_type(4)));

#define S_LEN 4096
#define NBATCH 2
#define EDIM 1024
#define DDIM 64
#define MROWS (NBATCH * S_LEN)   // 8192
#define NCOLS 192                // Q|K|V concatenated

union frag_u { bf16x8 v; bf16 e[8]; };

// ---------------------------------------------------------------------------
// Pack weights (f32 in) -> split bf16 hi/lo, layout Wt[3][64][1024]
// (n-major rows, contiguous in k) so MFMA B-fragments are 16B loads.
// ---------------------------------------------------------------------------
__global__ __launch_bounds__(256) void pack_w_kernel(
    const float* __restrict__ Wq, const float* __restrict__ Wk,
    const float* __restrict__ Wv, bf16* __restrict__ Wt_hi,
    bf16* __restrict__ Wt_lo) {
  int idx = blockIdx.x * 256 + threadIdx.x;   // 0 .. 3*64*1024-1
  int mat = idx >> 16;                        // 65536 elements per matrix
  int rem = idx & 65535;
  int n = rem >> 10;
  int k = rem & 1023;
  const float* W = (mat == 0) ? Wq : ((mat == 1) ? Wk : Wv);
  float v = W[k * DDIM + n];
  bf16 h = __float2bfloat16(v);
  float lo = v - __bfloat162float(h);
  Wt_hi[idx] = h;
  Wt_lo[idx] = __float2bfloat16(lo);
}

// ---------------------------------------------------------------------------
// Fused QKV GEMM, f32 inputs via split-bf16 MFMA (xh*wh + xh*wl + xl*wh).
// M=8192, K=1024, N=192. mfma_f32_16x16x32_bf16.
//   A-frag: A[m][k], m = lane&15, k = (lane>>4)*8 + j   (8 contiguous k)
//   B-frag: B[k][n], n = lane&15, k = (lane>>4)*8 + j
//   D:      D[m][n], m = (lane>>4)*4 + reg, n = lane&15
// Block = 16 rows; its 4 waves split the 12 n-tiles (3 each). Grid = 512
// (2 blocks/CU). x converted f32 -> hi/lo bf16 on the fly (in-register).
// ---------------------------------------------------------------------------
__global__ __launch_bounds__(256) void qkv_gemm_kernel(
    const float* __restrict__ x, const bf16* __restrict__ Wt_hi,
    const bf16* __restrict__ Wt_lo, const float* __restrict__ bq,
    const float* __restrict__ bk, const float* __restrict__ bv,
    float* __restrict__ qkv) {
  const int lane = threadIdx.x & 63;
  const int wave = threadIdx.x >> 6;          // nt = wave*3 + t
  const int quad = lane >> 4;
  const int l16 = lane & 15;
  const int rowBase = blockIdx.x * 16;

  const float* xa = x + (size_t)(rowBase + l16) * EDIM + quad * 8;

  f32x4 acc[3];
#pragma unroll
  for (int t = 0; t < 3; t++) acc[t] = (f32x4){0.f, 0.f, 0.f, 0.f};

  for (int k0 = 0; k0 < EDIM; k0 += 32) {
    float4 v0 = *(const float4*)(const void*)(xa + k0);
    float4 v1 = *(const float4*)(const void*)(xa + k0 + 4);
    float vv[8] = {v0.x, v0.y, v0.z, v0.w, v1.x, v1.y, v1.z, v1.w};
    frag_u ahi, alo;
#pragma unroll
    for (int e = 0; e < 8; e++) {
      bf16 h = __float2bfloat16(vv[e]);
      ahi.e[e] = h;
      alo.e[e] = __float2bfloat16(vv[e] - __bfloat162float(h));
    }
#pragma unroll
    for (int t = 0; t < 3; t++) {
      int nt = wave * 3 + t;
      size_t off = (size_t)(nt * 16 + l16) * EDIM + quad * 8 + k0;
      bf16x8 bh = *(const bf16x8*)(const void*)(Wt_hi + off);
      bf16x8 bl = *(const bf16x8*)(const void*)(Wt_lo + off);
      acc[t] = __builtin_amdgcn_mfma_f32_16x16x32_bf16(ahi.v, bh, acc[t], 0, 0, 0);
      acc[t] = __builtin_amdgcn_mfma_f32_16x16x32_bf16(ahi.v, bl, acc[t], 0, 0, 0);
      acc[t] = __builtin_amdgcn_mfma_f32_16x16x32_bf16(alo.v, bh, acc[t], 0, 0, 0);
    }
  }

#pragma unroll
  for (int t = 0; t < 3; t++) {
    int n = (wave * 3 + t) * 16 + l16;
    int mat = n >> 6;
    int col = n & 63;
    float bias = (mat == 0) ? bq[col] : ((mat == 1) ? bk[col] : bv[col]);
    float* dst = qkv + (size_t)mat * MROWS * DDIM +
                 (size_t)(rowBase + quad * 4) * DDIM + col;
#pragma unroll
    for (int r = 0; r < 4; r++) dst[r * DDIM] = acc[t][r] + bias;
  }
}

// ---------------------------------------------------------------------------
// Per-batch column sums of V (for the exp(0) background term).
// Grid = 64 blocks: b = blk>>5, 128-row chunk = blk&31. atomicAdd into Vsum.
// ---------------------------------------------------------------------------
__global__ __launch_bounds__(256) void vsum_kernel(const float* __restrict__ Vf,
                                                   float* __restrict__ Vsum) {
  int b = blockIdx.x >> 5;
  int chunk = blockIdx.x & 31;
  int col = threadIdx.x & 63;
  int rg = threadIdx.x >> 6;
  const float* base =
      Vf + ((size_t)b * S_LEN + chunk * 128 + rg * 32) * DDIM + col;
  float s = 0.f;
#pragma unroll
  for (int r = 0; r < 32; r++) s += base[r * DDIM];
  __shared__ float red[256];
  red[threadIdx.x] = s;
  __syncthreads();
  if (threadIdx.x < 64)
    atomicAdd(&Vsum[b * DDIM + col],
              red[col] + red[col + 64] + red[col + 128] + red[col + 192]);
}

// ---------------------------------------------------------------------------
// Attention: one wave per query. Lane d owns dim d of q/k/v.
// Softmax over the full row collapses to: 5 window exps + (S - nvalid)
// background exp(0-m) terms; background numerator = Vsum - sum(window V).
// Output is FLOAT32 (reference dataflow is all-f32).
// ---------------------------------------------------------------------------
__global__ __launch_bounds__(256) void attn_kernel(
    const float* __restrict__ Qf, const float* __restrict__ Kf,
    const float* __restrict__ Vf, const float* __restrict__ Vsum,
    float* __restrict__ out) {
  int lane = threadIdx.x & 63;
  int qidx = blockIdx.x * 4 + (threadIdx.x >> 6);
  int b = qidx >> 12;
  int i = qidx & 4095;

  float q = Qf[(size_t)qidx * DDIM + lane];
  float sc[5], vv[5];
  bool val[5];
#pragma unroll
  for (int w = 0; w < 5; w++) {
    int j = i + 2 * w - 4;               // DIL*(w - WIN/2), DIL=2
    val[w] = (j >= 0) && (j < S_LEN);
    int jj = val[w] ? j : i;
    size_t off = (size_t)(b * S_LEN + jj) * DDIM + lane;
    float kk = Kf[off];
    vv[w] = Vf[off];
    float p = q * kk;
#pragma unroll
    for (int d = 1; d < 64; d <<= 1) p += __shfl_xor(p, d, 64);
    sc[w] = p;
  }

  float mx = 0.f;  // include the background score 0 in the max
#pragma unroll
  for (int w = 0; w < 5; w++)
    if (val[w]) mx = fmaxf(mx, sc[w]);

  float denom = 0.f, accv = 0.f, vsel = 0.f;
  int nval = 0;
#pragma unroll
  for (int w = 0; w < 5; w++)
    if (val[w]) {
      float p = __expf(sc[w] - mx);
      denom += p;
      accv += p * vv[w];
      vsel += vv[w];
      nval++;
    }
  float p0 = __expf(-mx);
  denom += p0 * (float)(S_LEN - nval);
  accv += p0 * (Vsum[b * DDIM + lane] - vsel);

  out[(size_t)qidx * DDIM + lane] = accv / denom;
}

// ---------------------------------------------------------------------------
extern "C" void kernel_launch(void* const* d_in, const int* in_sizes, int n_in,
                              void* d_out, int out_size, void* d_ws,
                              size_t ws_size, hipStream_t stream) {
  const float* x = (const float*)d_in[0];
  const float* Wq = (const float*)d_in[1];
  const float* bq = (const float*)d_in[2];
  const float* Wk = (const float*)d_in[3];
  const float* bk = (const float*)d_in[4];
  const float* Wv = (const float*)d_in[5];
  const float* bv = (const float*)d_in[6];
  float* out = (float*)d_out;   // reference output dtype is float32

  char* ws = (char*)d_ws;
  bf16* Wt_hi = (bf16*)ws;                    // 393216 B
  bf16* Wt_lo = (bf16*)(ws + 393216);         // 393216 B
  float* qkv = (float*)(ws + 786432);         // 3*8192*64*4 = 6291456 B
  float* Qf = qkv;
  float* Kf = qkv + (size_t)MROWS * DDIM;
  float* Vf = Kf + (size_t)MROWS * DDIM;
  float* Vsum = (float*)(ws + 786432 + 6291456);  // 128 floats
  // total workspace: ~7.08 MB

  hipMemsetAsync(Vsum, 0, NBATCH * DDIM * sizeof(float), stream);
  hipLaunchKernelGGL(pack_w_kernel, dim3(768), dim3(256), 0, stream, Wq, Wk, Wv,
                     Wt_hi, Wt_lo);
  hipLaunchKernelGGL(qkv_gemm_kernel, dim3(512), dim3(256), 0, stream, x, Wt_hi,
                     Wt_lo, bq, bk, bv, qkv);
  hipLaunchKernelGGL(vsum_kernel, dim3(64), dim3(256), 0, stream, Vf, Vsum);
  hipLaunchKernelGGL(attn_kernel, dim3(2048), dim3(256), 0, stream, Qf, Kf, Vf,
                     Vsum, out);
}